// Round 6
// baseline (370.081 us; speedup 1.0000x reference)
//
#include <hip/hip_runtime.h>
#include <math.h>

// DigitCaps dynamic routing, MI355X (gfx950). Round 6: occupancy fix.
// B=256, I=1152 (dim 8), O=10 (dim 16), 3 routing iters.
//
// Round-5 post-mortem: k_pass was latency-bound at 2 blocks/CU (LDS 58 KB).
// Fix: pacc[4][16][160] (40 KB) -> pacc[16][160] (10 KB) accumulated with
// LDS ds_add_f32 atomics from lane<16 after the in-wave il-reduce.
// LDS = 8 (xs) + 10 (vs_s) + 10 (pacc) = 28.7 KB -> 5 blocks/CU = 20 waves.
// __launch_bounds__(256,5) caps VGPR at 102 (round-5 build used 88).
//
// b_ij identity: logits at iter k = u . (v0+..+v_{k-1}) = u . vsum -> b_ij is
// never materialized; vsum[256][160] lives in ws (tiny).
//
// Pipeline (6 kernels):
//  K1 k_pass<0>: u = W@x, partial[72][256][160] = per-itile sums of u.
//  K2 k_squash<0>: reduce 72, *0.1, squash -> vsum = v0.
//  K3 k_pass<1>: recompute u, c = softmax_o(u.vsum), partial = sums of c*u.
//  K4 k_squash<1>: vsum += v1.
//  K5 k_pass<1> again.
//  K6 k_squash<2>: out = v2.

constexpr int Bc  = 256;
constexpr int Ic  = 1152;
constexpr int Oc  = 10;
constexpr int DOc = 16;
constexpr int ODc = 160;
constexpr int ITILES = 72;

// Sum over the aligned 16-lane group, result in all 16 lanes. Pure VALU (DPP).
__device__ __forceinline__ float dpp16_sum(float v) {
    int s;
    s = __builtin_amdgcn_update_dpp(0, __float_as_int(v), 0xB1, 0xF, 0xF, true);
    v += __int_as_float(s);
    s = __builtin_amdgcn_update_dpp(0, __float_as_int(v), 0x4E, 0xF, 0xF, true);
    v += __int_as_float(s);
    s = __builtin_amdgcn_update_dpp(0, __float_as_int(v), 0x124, 0xF, 0xF, true);
    v += __int_as_float(s);
    s = __builtin_amdgcn_update_dpp(0, __float_as_int(v), 0x128, 0xF, 0xF, true);
    v += __int_as_float(s);
    return v;
}

// ---------------------------------------------------------------- K1/K3/K5
// grid 1152 = 72 itiles x 16 btiles, 256 threads.
// Thread (il = t>>4, d = t&15) owns capsule i = itile*16+il, out-dim d; its
// 80 W floats live in registers and are reused across the 16 b of the btile.
template <int PASS>
__global__ __launch_bounds__(256, 5) void k_pass(const float* __restrict__ x,
                                                 const float* __restrict__ W,
                                                 const float* __restrict__ vsum,
                                                 float* __restrict__ partial) {
    const int bx    = blockIdx.x;
    const int itile = bx % ITILES;
    const int btile = bx / ITILES;
    const int t     = threadIdx.x;
    const int d     = t & 15;
    const int il    = t >> 4;
    const int i     = itile * 16 + il;
    const int b0    = btile * 16;

    __shared__ __align__(16) float xs[16 * 128];    //  8 KB [bb][il*8+k]
    __shared__ __align__(16) float pacc[16 * ODc];  // 10 KB [bb][od], atomics
    __shared__ __align__(16) float vs_s[16 * ODc];  // 10 KB [bb][od]

    // stage x[b0:b0+16][itile*16:+16][8]
#pragma unroll
    for (int j = 0; j < 2; ++j) {
        int e  = t + j * 256;           // float4 index, 512 total
        int bb = e >> 5;
        int r  = e & 31;
        ((float4*)xs)[e] =
            ((const float4*)(x + (size_t)(b0 + bb) * (Ic * 8) + itile * 128))[r];
    }
    if (PASS == 1) {
        const float4* vg = (const float4*)(vsum + (size_t)b0 * ODc);
#pragma unroll
        for (int j = 0; j < 3; ++j) {
            int e = t + j * 256;
            if (e < 640) ((float4*)vs_s)[e] = vg[e];
        }
    }
    // zero pacc: 2560 floats / 256 threads = 10 each
#pragma unroll
    for (int j = 0; j < 10; ++j) pacc[t + j * 256] = 0.f;

    // W fragment for (i, d): 10 o x 8 k = 80 floats in registers
    float4 wr[20];
    {
        const float4* wp = (const float4*)(W + (((size_t)i * Oc) * DOc + d) * 8);
#pragma unroll
        for (int o = 0; o < Oc; ++o) {
            wr[2 * o]     = wp[o * 32];
            wr[2 * o + 1] = wp[o * 32 + 1];
        }
    }
    __syncthreads();

#pragma unroll 1
    for (int bb = 0; bb < 16; ++bb) {
        const float4 xa = *((const float4*)(xs + bb * 128 + il * 8));
        const float4 xb = *((const float4*)(xs + bb * 128 + il * 8 + 4));
        float u[Oc];
#pragma unroll
        for (int o = 0; o < Oc; ++o) {
            float4 w0 = wr[2 * o], w1 = wr[2 * o + 1];
            u[o] = w0.x * xa.x + w0.y * xa.y + w0.z * xa.z + w0.w * xa.w +
                   w1.x * xb.x + w1.y * xb.y + w1.z * xb.z + w1.w * xb.w;
        }
        float contrib[Oc];
        if (PASS == 1) {
            float c[Oc];
#pragma unroll
            for (int o = 0; o < Oc; ++o)
                c[o] = dpp16_sum(u[o] * vs_s[bb * ODc + o * 16 + d]);
            float m = c[0];
#pragma unroll
            for (int o = 1; o < Oc; ++o) m = fmaxf(m, c[o]);
            float se = 0.f;
#pragma unroll
            for (int o = 0; o < Oc; ++o) {
                c[o] = __expf(c[o] - m);
                se += c[o];
            }
            const float inv = 1.f / se;
#pragma unroll
            for (int o = 0; o < Oc; ++o) contrib[o] = (c[o] * inv) * u[o];
        } else {
            // iter 0: softmax(0) = 1/10 exactly; 0.1 folded into squash pre.
#pragma unroll
            for (int o = 0; o < Oc; ++o) contrib[o] = u[o];
        }
        // in-wave il-reduce (4 values), then lane<16 accumulates via LDS atomic
#pragma unroll
        for (int o = 0; o < Oc; ++o) {
            float a = contrib[o];
            a += __shfl_xor(a, 16);
            a += __shfl_xor(a, 32);
            if ((t & 63) < 16)
                atomicAdd(&pacc[bb * ODc + o * 16 + (t & 15)], a);
        }
    }
    __syncthreads();
    // partial[itile][b0+bb][od]
#pragma unroll
    for (int j = 0; j < 10; ++j) {
        int e = t + j * 256;            // bb*160+od, 2560 total
        partial[(size_t)itile * (Bc * ODc) + b0 * ODc + e] = pacc[e];
    }
}

// ---------------------------------------------------------------- K2/K4/K6
// MODE 0: vsum = v   MODE 1: vsum += v   MODE 2: out = v
template <int MODE>
__global__ __launch_bounds__(256) void k_squash(const float* __restrict__ part,
                                                float* __restrict__ vsum,
                                                float* __restrict__ out,
                                                float pre) {
    const int b = blockIdx.x;
    const int t = threadIdx.x;
    if (t >= ODc) return;
    float s = 0.f;
#pragma unroll 8
    for (int p = 0; p < ITILES; ++p)
        s += part[(size_t)p * (Bc * ODc) + b * ODc + t];
    s *= pre;
    float sq = dpp16_sum(s * s);
    float scale = sq / ((1.f + sq) * sqrtf(sq));
    float v = s * scale;
    if (MODE == 0) vsum[b * ODc + t] = v;
    if (MODE == 1) vsum[b * ODc + t] += v;
    if (MODE == 2) out[(size_t)b * ODc + t] = v;
}

// ---------------------------------------------------------------- fallback
__global__ void __launch_bounds__(1024, 4)
digitcaps_fallback(const float* __restrict__ x, const float* __restrict__ W,
                   float* __restrict__ out) {
    const int b = blockIdx.x, t = threadIdx.x;
    const int lane = t & 63, wid = t >> 6, d = t & 15, iblk = t >> 4;
    __shared__ __align__(16) float xs[Ic * 8];
    __shared__ __align__(16) float red[16 * ODc];
    __shared__ __align__(16) float svec[ODc], vcur[ODc], vsum[ODc];
    {
        const float4* xg = (const float4*)(x + (size_t)b * (Ic * 8));
        float4* xl = (float4*)xs;
        for (int j = t; j < Ic * 2; j += 1024) xl[j] = xg[j];
    }
    if (t < ODc) vsum[t] = 0.f;
    __syncthreads();
    float acc[Oc], vsr[Oc];
    for (int it = 0; it < 3; ++it) {
#pragma unroll
        for (int o = 0; o < Oc; ++o) { acc[o] = 0.f; vsr[o] = vsum[o * 16 + d]; }
#pragma unroll 1
        for (int chk = 0; chk < 18; ++chk) {
            const int i = chk * 64 + iblk;
            const float4 xa = ((const float4*)(xs + i * 8))[0];
            const float4 xb = ((const float4*)(xs + i * 8))[1];
            const float* wb = W + (((size_t)i * Oc) * DOc + d) * 8;
            float uo[Oc];
#pragma unroll
            for (int o = 0; o < Oc; ++o) {
                const float4* wp = (const float4*)(wb + o * 128);
                float4 w0 = wp[0], w1 = wp[1];
                uo[o] = w0.x * xa.x + w0.y * xa.y + w0.z * xa.z + w0.w * xa.w +
                        w1.x * xb.x + w1.y * xb.y + w1.z * xb.z + w1.w * xb.w;
            }
            float cc[Oc];
            if (it > 0) {
#pragma unroll
                for (int o = 0; o < Oc; ++o) cc[o] = dpp16_sum(uo[o] * vsr[o]);
                float m = cc[0];
#pragma unroll
                for (int o = 1; o < Oc; ++o) m = fmaxf(m, cc[o]);
                float se = 0.f;
#pragma unroll
                for (int o = 0; o < Oc; ++o) { cc[o] = __expf(cc[o] - m); se += cc[o]; }
                float inv = 1.f / se;
#pragma unroll
                for (int o = 0; o < Oc; ++o) acc[o] += cc[o] * inv * uo[o];
            } else {
#pragma unroll
                for (int o = 0; o < Oc; ++o) acc[o] += 0.1f * uo[o];
            }
        }
#pragma unroll
        for (int o = 0; o < Oc; ++o) {
            float a = acc[o];
            a += __shfl_xor(a, 16);
            a += __shfl_xor(a, 32);
            if (lane < 16) red[wid * ODc + o * 16 + lane] = a;
        }
        __syncthreads();
        if (t < ODc) {
            float s = 0.f;
#pragma unroll
            for (int w = 0; w < 16; ++w) s += red[w * ODc + t];
            svec[t] = s;
        }
        __syncthreads();
        if (t < Oc) {
            float sq = 0.f;
#pragma unroll
            for (int dd = 0; dd < DOc; ++dd) sq += svec[t * 16 + dd] * svec[t * 16 + dd];
            float sc = sq / ((1.f + sq) * sqrtf(sq));
#pragma unroll
            for (int dd = 0; dd < DOc; ++dd) {
                float v = svec[t * 16 + dd] * sc;
                vcur[t * 16 + dd] = v;
                vsum[t * 16 + dd] += v;
            }
        }
        __syncthreads();
    }
    if (t < ODc) out[(size_t)b * ODc + t] = vcur[t];
}

// ---------------------------------------------------------------- launcher
extern "C" void kernel_launch(void* const* d_in, const int* in_sizes, int n_in,
                              void* d_out, int out_size, void* d_ws, size_t ws_size,
                              hipStream_t stream) {
    (void)in_sizes; (void)n_in; (void)out_size;
    const float* x = (const float*)d_in[0];   // [256,1152,8]
    const float* W = (const float*)d_in[1];   // [1152,10,16,8]
    float* out     = (float*)d_out;           // [256,10,16]

    const size_t PART_B = (size_t)ITILES * Bc * ODc * sizeof(float); // 11.8 MB
    const size_t VSUM_B = (size_t)Bc * ODc * sizeof(float);          // 160 KB

    float* partial = (float*)d_ws;
    float* vsum    = (float*)((char*)d_ws + PART_B);

    if (ws_size >= PART_B + VSUM_B) {
        dim3 pg(ITILES * 16), pb(256);
        hipLaunchKernelGGL((k_pass<0>), pg, pb, 0, stream, x, W, nullptr, partial);
        hipLaunchKernelGGL((k_squash<0>), dim3(Bc), dim3(256), 0, stream,
                           partial, vsum, out, 0.1f);
        hipLaunchKernelGGL((k_pass<1>), pg, pb, 0, stream, x, W, vsum, partial);
        hipLaunchKernelGGL((k_squash<1>), dim3(Bc), dim3(256), 0, stream,
                           partial, vsum, out, 1.f);
        hipLaunchKernelGGL((k_pass<1>), pg, pb, 0, stream, x, W, vsum, partial);
        hipLaunchKernelGGL((k_squash<2>), dim3(Bc), dim3(256), 0, stream,
                           partial, vsum, out, 1.f);
    } else {
        hipLaunchKernelGGL(digitcaps_fallback, dim3(Bc), dim3(1024), 0, stream,
                           x, W, out);
    }
}

// Round 7
// 253.702 us; speedup vs baseline: 1.4587x; 1.4587x over previous
//
#include <hip/hip_runtime.h>
#include <hip/hip_fp16.h>
#include <math.h>

// DigitCaps dynamic routing, MI355X (gfx950). Round 7: R4 pipeline with the
// two measured hot spots fixed.
// B=256, I=1152 (dim 8), O=10 (dim 16), 3 routing iters.
//
//  - K1 (u_hat): R4 structure (W in registers, per-wave LDS pacc, NO atomics,
//    NO masked branches -> compiler keeps wr[20] resident; R6 showed atomics+
//    branch collapse VGPR to 48 and force W re-reads). bb=8 per block shrinks
//    LDS 48.6->24.6 KB => 6 blocks/CU (launch_bounds(256,6), budget 85 >= 68).
//  - k_route: R4 structure but logit dot-products via DPP (quad_perm xor1/xor2
//    + row_ror:4/8), removing ~360 ds_swizzle per thread (~29 us of DS-pipe
//    serialization per pass). DPP reduce validated on HW in R5/R6.
//  - b_ij identity: logits at iter k = u.(v0+..+v_{k-1}) = u.vsum.
//
// Pipeline: K1 u_hat+s0-partials -> squash<72,0> -> route -> squash<2,1>
//           -> route -> squash<2,2> -> out.

constexpr int Bc  = 256;
constexpr int Ic  = 1152;
constexpr int Oc  = 10;
constexpr int DOc = 16;
constexpr int ODc = 160;
constexpr int ITILES = 72;
constexpr int BB  = 8;              // b per K1 block
constexpr int BT  = Bc / BB;        // 32 btiles

// Sum over the aligned 16-lane group, result in all 16 lanes. Pure VALU (DPP).
__device__ __forceinline__ float dpp16_sum(float v) {
    int s;
    s = __builtin_amdgcn_update_dpp(0, __float_as_int(v), 0xB1, 0xF, 0xF, true);
    v += __int_as_float(s);
    s = __builtin_amdgcn_update_dpp(0, __float_as_int(v), 0x4E, 0xF, 0xF, true);
    v += __int_as_float(s);
    s = __builtin_amdgcn_update_dpp(0, __float_as_int(v), 0x124, 0xF, 0xF, true);
    v += __int_as_float(s);
    s = __builtin_amdgcn_update_dpp(0, __float_as_int(v), 0x128, 0xF, 0xF, true);
    v += __int_as_float(s);
    return v;
}

// ---------------------------------------------------------------- K1
// grid 72 itiles x 32 btiles, 256 threads. Thread (il=t>>4, d=t&15) owns
// capsule i = itile*16+il, out-dim d; its 80 W floats live in registers and
// are reused across the 8 b of the btile. Writes fp16 ws + s0 partials.
__global__ __launch_bounds__(256, 6) void k_uhat(const float* __restrict__ x,
                                                 const float* __restrict__ W,
                                                 __half2* __restrict__ uws,
                                                 float* __restrict__ partial) {
    const int bx    = blockIdx.x;
    const int itile = bx % ITILES;      // 72%8==0: itile spreads across XCDs
    const int btile = bx / ITILES;      // 0..31
    const int t     = threadIdx.x;
    const int d     = t & 15;
    const int il    = t >> 4;
    const int w     = t >> 6;
    const int i     = itile * 16 + il;
    const int b0    = btile * BB;

    __shared__ __align__(16) float xs[BB * 128];        //  4 KB [bb][il*8+k]
    __shared__ __align__(16) float pacc[4 * BB * ODc];  // 20 KB [w][bb][od]

    // stage x[b0:b0+8][itile*16:+16][8]: 256 float4, one per thread
    {
        int bb = t >> 5;
        int r  = t & 31;
        ((float4*)xs)[t] =
            ((const float4*)(x + (size_t)(b0 + bb) * (Ic * 8) + itile * 128))[r];
    }

    // W fragment for (i, d): 10 o x 8 k = 80 floats in registers
    float4 wr[20];
    {
        const float4* wp = (const float4*)(W + (((size_t)i * Oc) * DOc + d) * 8);
#pragma unroll
        for (int o = 0; o < Oc; ++o) {
            wr[2 * o]     = wp[o * 32];
            wr[2 * o + 1] = wp[o * 32 + 1];
        }
    }
    __syncthreads();

    const int ch    = i >> 6;
    const int off_t = (i & 63) * 16 + d;

#pragma unroll 1
    for (int bb = 0; bb < BB; ++bb) {
        const int b = b0 + bb;
        const float4 xa = *((const float4*)(xs + bb * 128 + il * 8));
        const float4 xb = *((const float4*)(xs + bb * 128 + il * 8 + 4));
        float u[Oc];
#pragma unroll
        for (int o = 0; o < Oc; ++o) {
            float4 w0 = wr[2 * o], w1 = wr[2 * o + 1];
            u[o] = w0.x * xa.x + w0.y * xa.y + w0.z * xa.z + w0.w * xa.w +
                   w1.x * xb.x + w1.y * xb.y + w1.z * xb.z + w1.w * xb.w;
        }
        // fp16 ws write, coalesced (off_t consecutive over t)
        __half2* ub = uws + ((size_t)b * 90 + ch * 5) * 1024 + off_t;
#pragma unroll
        for (int op = 0; op < 5; ++op)
            ub[op * 1024] = __floats2half2_rn(u[2 * op], u[2 * op + 1]);
        // reduce over the wave's 4 il values; lane<16 holds (o,d) sums
#pragma unroll
        for (int o = 0; o < Oc; ++o) {
            float a = u[o];
            a += __shfl_xor(a, 16);
            a += __shfl_xor(a, 32);
            if ((t & 63) < 16) pacc[(w * BB + bb) * ODc + o * 16 + d] = a;
        }
    }
    __syncthreads();
    // partial[itile][b0+bb][od]: BB*160 = 1280 floats, 5 per thread
#pragma unroll
    for (int j = 0; j < 5; ++j) {
        int e = t + j * 256;            // bb*160+od
        float s = pacc[e] + pacc[BB * ODc + e] + pacc[2 * BB * ODc + e] +
                  pacc[3 * BB * ODc + e];
        partial[(size_t)itile * (Bc * ODc) + b0 * ODc + e] = s;
    }
}

// ---------------------------------------------------------------- squash
// MODE 0: vsum = v   MODE 1: vsum += v   MODE 2: out = v
template <int P, int MODE>
__global__ __launch_bounds__(256) void k_squash(const float* __restrict__ part,
                                                float* __restrict__ vsum,
                                                float* __restrict__ out,
                                                float pre) {
    const int b = blockIdx.x;
    const int t = threadIdx.x;
    if (t >= ODc) return;
    float s = 0.f;
#pragma unroll 8
    for (int p = 0; p < P; ++p)
        s += part[(size_t)p * (Bc * ODc) + b * ODc + t];
    s *= pre;
    float sq = dpp16_sum(s * s);
    float scale = sq / ((1.f + sq) * sqrtf(sq));
    float v = s * scale;
    if (MODE == 0) vsum[b * ODc + t] = v;
    if (MODE == 1) vsum[b * ODc + t] += v;
    if (MODE == 2) out[(size_t)b * ODc + t] = v;
}

// ---------------------------------------------------------------- route
// grid 512 = b x i-half, 1024 threads (32 waves/CU at 2 blocks).
// t = iblk*16 + d, iblk 0..63 covering i = (h*9+ch)*64 + iblk.
__global__ __launch_bounds__(1024, 8) void k_route(const __half2* __restrict__ uws,
                                                   const float* __restrict__ vsum,
                                                   float* __restrict__ spart) {
    const int bx  = blockIdx.x;
    const int b   = bx >> 1;
    const int h   = bx & 1;
    const int t   = threadIdx.x;
    const int d   = t & 15;
    const int wid = t >> 6;

    __shared__ float vs_s[ODc];
    __shared__ float red[16 * ODc];     // 10 KB
    if (t < ODc) vs_s[t] = vsum[b * ODc + t];
    __syncthreads();

    float vsr[Oc];
#pragma unroll
    for (int o = 0; o < Oc; ++o) vsr[o] = vs_s[o * 16 + d];
    float acc[Oc];
#pragma unroll
    for (int o = 0; o < Oc; ++o) acc[o] = 0.f;

    const __half2* wsb = uws + ((size_t)b * 90 + h * 45) * 1024 + t;
#pragma unroll 1
    for (int ch = 0; ch < 9; ++ch) {
        float uo[Oc];
#pragma unroll
        for (int op = 0; op < 5; ++op) {
            float2 f = __half22float2(wsb[(ch * 5 + op) * 1024]);
            uo[2 * op]     = f.x;
            uo[2 * op + 1] = f.y;
        }
        // logits via DPP 16-lane reduce (VALU, no DS traffic)
        float c[Oc];
#pragma unroll
        for (int o = 0; o < Oc; ++o) c[o] = dpp16_sum(uo[o] * vsr[o]);
        float m = c[0];
#pragma unroll
        for (int o = 1; o < Oc; ++o) m = fmaxf(m, c[o]);
        float se = 0.f;
#pragma unroll
        for (int o = 0; o < Oc; ++o) {
            c[o] = __expf(c[o] - m);
            se += c[o];
        }
        const float inv = 1.f / se;
#pragma unroll
        for (int o = 0; o < Oc; ++o) acc[o] += (c[o] * inv) * uo[o];
    }
    // block reduce over iblk (only 20 DS shuffles/thread, once per pass)
#pragma unroll
    for (int o = 0; o < Oc; ++o) {
        float a = acc[o];
        a += __shfl_xor(a, 16);
        a += __shfl_xor(a, 32);
        if ((t & 63) < 16) red[wid * ODc + o * 16 + d] = a;
    }
    __syncthreads();
    if (t < ODc) {
        float s = 0.f;
#pragma unroll
        for (int w = 0; w < 16; ++w) s += red[w * ODc + t];
        spart[(size_t)h * (Bc * ODc) + b * ODc + t] = s;
    }
}

// ---------------------------------------------------------------- fallback
__global__ void __launch_bounds__(1024, 4)
digitcaps_fallback(const float* __restrict__ x, const float* __restrict__ W,
                   float* __restrict__ out) {
    const int b = blockIdx.x, t = threadIdx.x;
    const int lane = t & 63, wid = t >> 6, d = t & 15, iblk = t >> 4;
    __shared__ __align__(16) float xs[Ic * 8];
    __shared__ __align__(16) float red[16 * ODc];
    __shared__ __align__(16) float svec[ODc], vcur[ODc], vsum[ODc];
    {
        const float4* xg = (const float4*)(x + (size_t)b * (Ic * 8));
        float4* xl = (float4*)xs;
        for (int j = t; j < Ic * 2; j += 1024) xl[j] = xg[j];
    }
    if (t < ODc) vsum[t] = 0.f;
    __syncthreads();
    float acc[Oc], vsr[Oc];
    for (int it = 0; it < 3; ++it) {
#pragma unroll
        for (int o = 0; o < Oc; ++o) { acc[o] = 0.f; vsr[o] = vsum[o * 16 + d]; }
#pragma unroll 1
        for (int chk = 0; chk < 18; ++chk) {
            const int i = chk * 64 + iblk;
            const float4 xa = ((const float4*)(xs + i * 8))[0];
            const float4 xb = ((const float4*)(xs + i * 8))[1];
            const float* wb = W + (((size_t)i * Oc) * DOc + d) * 8;
            float uo[Oc];
#pragma unroll
            for (int o = 0; o < Oc; ++o) {
                const float4* wp = (const float4*)(wb + o * 128);
                float4 w0 = wp[0], w1 = wp[1];
                uo[o] = w0.x * xa.x + w0.y * xa.y + w0.z * xa.z + w0.w * xa.w +
                        w1.x * xb.x + w1.y * xb.y + w1.z * xb.z + w1.w * xb.w;
            }
            float cc[Oc];
            if (it > 0) {
#pragma unroll
                for (int o = 0; o < Oc; ++o) cc[o] = dpp16_sum(uo[o] * vsr[o]);
                float m = cc[0];
#pragma unroll
                for (int o = 1; o < Oc; ++o) m = fmaxf(m, cc[o]);
                float se = 0.f;
#pragma unroll
                for (int o = 0; o < Oc; ++o) { cc[o] = __expf(cc[o] - m); se += cc[o]; }
                float inv = 1.f / se;
#pragma unroll
                for (int o = 0; o < Oc; ++o) acc[o] += cc[o] * inv * uo[o];
            } else {
#pragma unroll
                for (int o = 0; o < Oc; ++o) acc[o] += 0.1f * uo[o];
            }
        }
#pragma unroll
        for (int o = 0; o < Oc; ++o) {
            float a = acc[o];
            a += __shfl_xor(a, 16);
            a += __shfl_xor(a, 32);
            if (lane < 16) red[wid * ODc + o * 16 + lane] = a;
        }
        __syncthreads();
        if (t < ODc) {
            float s = 0.f;
#pragma unroll
            for (int w = 0; w < 16; ++w) s += red[w * ODc + t];
            svec[t] = s;
        }
        __syncthreads();
        if (t < Oc) {
            float sq = 0.f;
#pragma unroll
            for (int dd = 0; dd < DOc; ++dd) sq += svec[t * 16 + dd] * svec[t * 16 + dd];
            float sc = sq / ((1.f + sq) * sqrtf(sq));
#pragma unroll
            for (int dd = 0; dd < DOc; ++dd) {
                float v = svec[t * 16 + dd] * sc;
                vcur[t * 16 + dd] = v;
                vsum[t * 16 + dd] += v;
            }
        }
        __syncthreads();
    }
    if (t < ODc) out[(size_t)b * ODc + t] = vcur[t];
}

// ---------------------------------------------------------------- launcher
extern "C" void kernel_launch(void* const* d_in, const int* in_sizes, int n_in,
                              void* d_out, int out_size, void* d_ws, size_t ws_size,
                              hipStream_t stream) {
    (void)in_sizes; (void)n_in; (void)out_size;
    const float* x = (const float*)d_in[0];   // [256,1152,8]
    const float* W = (const float*)d_in[1];   // [1152,10,16,8]
    float* out     = (float*)d_out;           // [256,10,16]

    const size_t UWS_B   = (size_t)Bc * 90 * 1024 * sizeof(__half2); // 94.37 MB
    const size_t PART_B  = (size_t)ITILES * Bc * ODc * sizeof(float); // 11.8 MB
    const size_t SPART_B = (size_t)2 * Bc * ODc * sizeof(float);      // 0.33 MB
    const size_t VSUM_B  = (size_t)Bc * ODc * sizeof(float);          // 0.16 MB

    __half2* uws   = (__half2*)d_ws;
    float* partial = (float*)((char*)d_ws + UWS_B);
    float* spart   = (float*)((char*)d_ws + UWS_B + PART_B);
    float* vsum    = (float*)((char*)d_ws + UWS_B + PART_B + SPART_B);

    if (ws_size >= UWS_B + PART_B + SPART_B + VSUM_B) {
        hipLaunchKernelGGL(k_uhat, dim3(ITILES * BT), dim3(256), 0, stream,
                           x, W, uws, partial);
        hipLaunchKernelGGL((k_squash<ITILES, 0>), dim3(Bc), dim3(256), 0, stream,
                           partial, vsum, out, 0.1f);
        hipLaunchKernelGGL(k_route, dim3(512), dim3(1024), 0, stream,
                           uws, vsum, spart);
        hipLaunchKernelGGL((k_squash<2, 1>), dim3(Bc), dim3(256), 0, stream,
                           spart, vsum, out, 1.f);
        hipLaunchKernelGGL(k_route, dim3(512), dim3(1024), 0, stream,
                           uws, vsum, spart);
        hipLaunchKernelGGL((k_squash<2, 2>), dim3(Bc), dim3(256), 0, stream,
                           spart, vsum, out, 1.f);
    } else {
        hipLaunchKernelGGL(digitcaps_fallback, dim3(Bc), dim3(1024), 0, stream,
                           x, W, out);
    }
}

// Round 8
// 150.197 us; speedup vs baseline: 2.4640x; 1.6891x over previous
//
#include <hip/hip_runtime.h>
#include <hip/hip_fp16.h>
#include <math.h>

// DigitCaps dynamic routing, MI355X (gfx950). Round 8: 4-kernel pipeline.
// B=256, I=1152 (dim 8), O=10 (dim 16), 3 routing iters.
//
// Lessons enforced here:
//  - K1 (k_uhat) is BYTE-IDENTICAL to round 4's proven 46 us kernel
//    (launch_bounds(256,4), bb=16, VGPR 68). (256,6)/(256,5)/atomics all made
//    the compiler spill the 80-float W fragment (R6: VGPR 48, R7: VGPR 40 with
//    ~265 MB of scratch spill traffic). Do not touch.
//  - k_squash<72> (1 block/CU, 160 threads, 72 strided loads) and two launch
//    gaps are folded INTO the route kernels: each route block reduces the
//    partials for its b inline (4 parallel thread-teams), squashes, routes.
//  - b_ij identity: logits at iter k = u.(v0+..+v_{k-1}) = u.vsum.
//
// Pipeline:
//  K1 k_uhat:      u = W@x -> fp16 ws + s0 partials[72][256][160].
//  K2 k_route<1>:  inline vsum0 = squash(0.1*sum72) (written to vsumg),
//                  route, spart1[2][256][160].
//  K3 k_route<2>:  inline v1 = squash(spart1), vsum = vsumg+v1, route,
//                  spart2[2][256][160].
//  K4 k_final:     out = squash(spart2).

constexpr int Bc  = 256;
constexpr int Ic  = 1152;
constexpr int Oc  = 10;
constexpr int DOc = 16;
constexpr int ODc = 160;
constexpr int ITILES = 72;

// Sum over the aligned 16-lane group, result in all 16 lanes. Pure VALU (DPP).
__device__ __forceinline__ float dpp16_sum(float v) {
    int s;
    s = __builtin_amdgcn_update_dpp(0, __float_as_int(v), 0xB1, 0xF, 0xF, true);
    v += __int_as_float(s);
    s = __builtin_amdgcn_update_dpp(0, __float_as_int(v), 0x4E, 0xF, 0xF, true);
    v += __int_as_float(s);
    s = __builtin_amdgcn_update_dpp(0, __float_as_int(v), 0x124, 0xF, 0xF, true);
    v += __int_as_float(s);
    s = __builtin_amdgcn_update_dpp(0, __float_as_int(v), 0x128, 0xF, 0xF, true);
    v += __int_as_float(s);
    return v;
}

// ---------------------------------------------------------------- K1
// EXACT round-4 kernel (46 us measured). grid 72 itiles x 16 btiles, 256 thr.
__global__ __launch_bounds__(256, 4) void k_uhat(const float* __restrict__ x,
                                                 const float* __restrict__ W,
                                                 __half2* __restrict__ uws,
                                                 float* __restrict__ partial) {
    const int bx    = blockIdx.x;
    const int itile = bx % ITILES;
    const int btile = bx / ITILES;
    const int t     = threadIdx.x;
    const int d     = t & 15;
    const int il    = t >> 4;
    const int w     = t >> 6;
    const int i     = itile * 16 + il;
    const int b0    = btile * 16;

    __shared__ __align__(16) float xs[16 * 128];        //  8 KB [bb][il*8+k]
    __shared__ __align__(16) float pacc[4 * 16 * ODc];  // 40 KB [w][bb][od]

    // stage x[b0:b0+16][itile*16:+16][8]
#pragma unroll
    for (int j = 0; j < 2; ++j) {
        int e  = t + j * 256;
        int bb = e >> 5;
        int r  = e & 31;
        ((float4*)xs)[e] =
            ((const float4*)(x + (size_t)(b0 + bb) * (Ic * 8) + itile * 128))[r];
    }

    // W fragment for (i, d): 10 o x 8 k = 80 floats in registers
    float4 wr[20];
    {
        const float4* wp = (const float4*)(W + (((size_t)i * Oc) * DOc + d) * 8);
#pragma unroll
        for (int o = 0; o < Oc; ++o) {
            wr[2 * o]     = wp[o * 32];
            wr[2 * o + 1] = wp[o * 32 + 1];
        }
    }
    __syncthreads();

    const int ch    = i >> 6;
    const int off_t = (i & 63) * 16 + d;

#pragma unroll 1
    for (int bb = 0; bb < 16; ++bb) {
        const int b = b0 + bb;
        const float4 xa = *((const float4*)(xs + bb * 128 + il * 8));
        const float4 xb = *((const float4*)(xs + bb * 128 + il * 8 + 4));
        float u[Oc];
#pragma unroll
        for (int o = 0; o < Oc; ++o) {
            float4 w0 = wr[2 * o], w1 = wr[2 * o + 1];
            u[o] = w0.x * xa.x + w0.y * xa.y + w0.z * xa.z + w0.w * xa.w +
                   w1.x * xb.x + w1.y * xb.y + w1.z * xb.z + w1.w * xb.w;
        }
        __half2* ub = uws + ((size_t)b * 90 + ch * 5) * 1024 + off_t;
#pragma unroll
        for (int op = 0; op < 5; ++op)
            ub[op * 1024] = __floats2half2_rn(u[2 * op], u[2 * op + 1]);
#pragma unroll
        for (int o = 0; o < Oc; ++o) {
            float a = u[o];
            a += __shfl_xor(a, 16);
            a += __shfl_xor(a, 32);
            if ((t & 63) < 16) pacc[(w * 16 + bb) * ODc + o * 16 + d] = a;
        }
    }
    __syncthreads();
#pragma unroll
    for (int j = 0; j < 10; ++j) {
        int e = t + j * 256;
        float s = pacc[e] + pacc[2560 + e] + pacc[5120 + e] + pacc[7680 + e];
        partial[(size_t)itile * (Bc * ODc) + b0 * ODc + e] = s;
    }
}

// ---------------------------------------------------------------- K2/K3
// grid 512 = b x i-half, 1024 threads, 2 blocks/CU (32 waves).
// PASS 1: vsum = squash(0.1 * sum_{p<72} partial[p]); also written to vsumg.
// PASS 2: vsum = vsumg + squash(spart1[0]+spart1[1]).
template <int PASS>
__global__ __launch_bounds__(1024, 8) void k_route(const __half2* __restrict__ uws,
                                                   const float* __restrict__ partial,
                                                   const float* __restrict__ sprev,
                                                   float* __restrict__ vsumg,
                                                   float* __restrict__ spart) {
    const int bx  = blockIdx.x;
    const int b   = bx >> 1;
    const int h   = bx & 1;
    const int t   = threadIdx.x;
    const int d   = t & 15;
    const int wid = t >> 6;

    __shared__ float vs_s[ODc];
    __shared__ float red4[4 * ODc];
    __shared__ float red[16 * ODc];     // 10 KB

    // ---- inline vsum computation ----
    if (PASS == 1) {
        // 4 teams of 160 threads each reduce 18 of the 72 partials
        const int team = t >> 8;        // 0..3
        const int tt   = t & 255;
        if (tt < ODc) {
            float s = 0.f;
            const float* pb = partial + (size_t)team * 18 * (Bc * ODc) + b * ODc + tt;
#pragma unroll 6
            for (int p = 0; p < 18; ++p) s += pb[(size_t)p * (Bc * ODc)];
            red4[team * ODc + tt] = s;
        }
        __syncthreads();
        if (t < ODc) {
            float s = (red4[t] + red4[ODc + t] + red4[2 * ODc + t] +
                       red4[3 * ODc + t]) * 0.1f;
            float sq = dpp16_sum(s * s);
            float v = s * (sq / ((1.f + sq) * sqrtf(sq)));
            vs_s[t] = v;
            vsumg[b * ODc + t] = v;     // both h-blocks write same value
        }
    } else {
        if (t < ODc) {
            float s = sprev[b * ODc + t] + sprev[(size_t)(Bc * ODc) + b * ODc + t];
            float sq = dpp16_sum(s * s);
            float v = s * (sq / ((1.f + sq) * sqrtf(sq)));
            vs_s[t] = vsumg[b * ODc + t] + v;
        }
    }
    __syncthreads();

    float vsr[Oc];
#pragma unroll
    for (int o = 0; o < Oc; ++o) vsr[o] = vs_s[o * 16 + d];
    float acc[Oc];
#pragma unroll
    for (int o = 0; o < Oc; ++o) acc[o] = 0.f;

    const __half2* wsb = uws + ((size_t)b * 90 + h * 45) * 1024 + t;
#pragma unroll 1
    for (int ch = 0; ch < 9; ++ch) {
        float uo[Oc];
#pragma unroll
        for (int op = 0; op < 5; ++op) {
            float2 f = __half22float2(wsb[(ch * 5 + op) * 1024]);
            uo[2 * op]     = f.x;
            uo[2 * op + 1] = f.y;
        }
        // logits via DPP 16-lane reduce (VALU, no DS traffic)
        float c[Oc];
#pragma unroll
        for (int o = 0; o < Oc; ++o) c[o] = dpp16_sum(uo[o] * vsr[o]);
        float m = c[0];
#pragma unroll
        for (int o = 1; o < Oc; ++o) m = fmaxf(m, c[o]);
        float se = 0.f;
#pragma unroll
        for (int o = 0; o < Oc; ++o) {
            c[o] = __expf(c[o] - m);
            se += c[o];
        }
        const float inv = 1.f / se;
#pragma unroll
        for (int o = 0; o < Oc; ++o) acc[o] += (c[o] * inv) * uo[o];
    }
    // block reduce over iblk
#pragma unroll
    for (int o = 0; o < Oc; ++o) {
        float a = acc[o];
        a += __shfl_xor(a, 16);
        a += __shfl_xor(a, 32);
        if ((t & 63) < 16) red[wid * ODc + o * 16 + d] = a;
    }
    __syncthreads();
    if (t < ODc) {
        float s = 0.f;
#pragma unroll
        for (int w = 0; w < 16; ++w) s += red[w * ODc + t];
        spart[(size_t)h * (Bc * ODc) + b * ODc + t] = s;
    }
}

// ---------------------------------------------------------------- K4
__global__ __launch_bounds__(192) void k_final(const float* __restrict__ spart,
                                               float* __restrict__ out) {
    const int b = blockIdx.x;
    const int t = threadIdx.x;
    if (t >= ODc) return;
    float s = spart[b * ODc + t] + spart[(size_t)(Bc * ODc) + b * ODc + t];
    float sq = dpp16_sum(s * s);
    float v = s * (sq / ((1.f + sq) * sqrtf(sq)));
    out[(size_t)b * ODc + t] = v;
}

// ---------------------------------------------------------------- fallback
__global__ void __launch_bounds__(1024, 4)
digitcaps_fallback(const float* __restrict__ x, const float* __restrict__ W,
                   float* __restrict__ out) {
    const int b = blockIdx.x, t = threadIdx.x;
    const int lane = t & 63, wid = t >> 6, d = t & 15, iblk = t >> 4;
    __shared__ __align__(16) float xs[Ic * 8];
    __shared__ __align__(16) float red[16 * ODc];
    __shared__ __align__(16) float svec[ODc], vcur[ODc], vsum[ODc];
    {
        const float4* xg = (const float4*)(x + (size_t)b * (Ic * 8));
        float4* xl = (float4*)xs;
        for (int j = t; j < Ic * 2; j += 1024) xl[j] = xg[j];
    }
    if (t < ODc) vsum[t] = 0.f;
    __syncthreads();
    float acc[Oc], vsr[Oc];
    for (int it = 0; it < 3; ++it) {
#pragma unroll
        for (int o = 0; o < Oc; ++o) { acc[o] = 0.f; vsr[o] = vsum[o * 16 + d]; }
#pragma unroll 1
        for (int chk = 0; chk < 18; ++chk) {
            const int i = chk * 64 + iblk;
            const float4 xa = ((const float4*)(xs + i * 8))[0];
            const float4 xb = ((const float4*)(xs + i * 8))[1];
            const float* wb = W + (((size_t)i * Oc) * DOc + d) * 8;
            float uo[Oc];
#pragma unroll
            for (int o = 0; o < Oc; ++o) {
                const float4* wp = (const float4*)(wb + o * 128);
                float4 w0 = wp[0], w1 = wp[1];
                uo[o] = w0.x * xa.x + w0.y * xa.y + w0.z * xa.z + w0.w * xa.w +
                        w1.x * xb.x + w1.y * xb.y + w1.z * xb.z + w1.w * xb.w;
            }
            float cc[Oc];
            if (it > 0) {
#pragma unroll
                for (int o = 0; o < Oc; ++o) cc[o] = dpp16_sum(uo[o] * vsr[o]);
                float m = cc[0];
#pragma unroll
                for (int o = 1; o < Oc; ++o) m = fmaxf(m, cc[o]);
                float se = 0.f;
#pragma unroll
                for (int o = 0; o < Oc; ++o) { cc[o] = __expf(cc[o] - m); se += cc[o]; }
                float inv = 1.f / se;
#pragma unroll
                for (int o = 0; o < Oc; ++o) acc[o] += cc[o] * inv * uo[o];
            } else {
#pragma unroll
                for (int o = 0; o < Oc; ++o) acc[o] += 0.1f * uo[o];
            }
        }
#pragma unroll
        for (int o = 0; o < Oc; ++o) {
            float a = acc[o];
            a += __shfl_xor(a, 16);
            a += __shfl_xor(a, 32);
            if (lane < 16) red[wid * ODc + o * 16 + lane] = a;
        }
        __syncthreads();
        if (t < ODc) {
            float s = 0.f;
#pragma unroll
            for (int w = 0; w < 16; ++w) s += red[w * ODc + t];
            svec[t] = s;
        }
        __syncthreads();
        if (t < Oc) {
            float sq = 0.f;
#pragma unroll
            for (int dd = 0; dd < DOc; ++dd) sq += svec[t * 16 + dd] * svec[t * 16 + dd];
            float sc = sq / ((1.f + sq) * sqrtf(sq));
#pragma unroll
            for (int dd = 0; dd < DOc; ++dd) {
                float v = svec[t * 16 + dd] * sc;
                vcur[t * 16 + dd] = v;
                vsum[t * 16 + dd] += v;
            }
        }
        __syncthreads();
    }
    if (t < ODc) out[(size_t)b * ODc + t] = vcur[t];
}

// ---------------------------------------------------------------- launcher
extern "C" void kernel_launch(void* const* d_in, const int* in_sizes, int n_in,
                              void* d_out, int out_size, void* d_ws, size_t ws_size,
                              hipStream_t stream) {
    (void)in_sizes; (void)n_in; (void)out_size;
    const float* x = (const float*)d_in[0];   // [256,1152,8]
    const float* W = (const float*)d_in[1];   // [1152,10,16,8]
    float* out     = (float*)d_out;           // [256,10,16]

    const size_t UWS_B   = (size_t)Bc * 90 * 1024 * sizeof(__half2);  // 94.37 MB
    const size_t PART_B  = (size_t)ITILES * Bc * ODc * sizeof(float); // 11.80 MB
    const size_t SP1_B   = (size_t)2 * Bc * ODc * sizeof(float);      //  0.33 MB
    const size_t SP2_B   = (size_t)2 * Bc * ODc * sizeof(float);      //  0.33 MB
    const size_t VSUM_B  = (size_t)Bc * ODc * sizeof(float);          //  0.16 MB

    __half2* uws   = (__half2*)d_ws;
    float* partial = (float*)((char*)d_ws + UWS_B);
    float* spart1  = (float*)((char*)d_ws + UWS_B + PART_B);
    float* spart2  = (float*)((char*)d_ws + UWS_B + PART_B + SP1_B);
    float* vsumg   = (float*)((char*)d_ws + UWS_B + PART_B + SP1_B + SP2_B);

    if (ws_size >= UWS_B + PART_B + SP1_B + SP2_B + VSUM_B) {
        hipLaunchKernelGGL(k_uhat, dim3(ITILES * 16), dim3(256), 0, stream,
                           x, W, uws, partial);
        hipLaunchKernelGGL((k_route<1>), dim3(512), dim3(1024), 0, stream,
                           uws, partial, nullptr, vsumg, spart1);
        hipLaunchKernelGGL((k_route<2>), dim3(512), dim3(1024), 0, stream,
                           uws, nullptr, spart1, vsumg, spart2);
        hipLaunchKernelGGL(k_final, dim3(Bc), dim3(192), 0, stream,
                           spart2, out);
    } else {
        hipLaunchKernelGGL(digitcaps_fallback, dim3(Bc), dim3(1024), 0, stream,
                           x, W, out);
    }
}